// Round 1
// baseline (2665.712 us; speedup 1.0000x reference)
//
#include <hip/hip_runtime.h>
#include <hip/hip_bf16.h>

// Problem constants (from reference): B=64, C=256, H=W=28, N=784
#define BB   64
#define CC   256
#define NPIX 784          // 28*28
#define BNP  (BB * NPIX)  // 50176 (waves per loss)

// ---------------------------------------------------------------------------
// Kernel 1: transpose [B,C,N] -> [B,N,C] for all four feature arrays.
// 64x64 LDS tile, coalesced on both sides, +1 padding kills bank conflicts.
// grid decomposition: bx = ((arr*64 + b)*4 + ct)*13 + nt
// ---------------------------------------------------------------------------
__global__ __launch_bounds__(256) void transpose_k(
    const float* __restrict__ y1, const float* __restrict__ y2,
    const float* __restrict__ z1, const float* __restrict__ z2,
    float* __restrict__ o1, float* __restrict__ o2,
    float* __restrict__ o3, float* __restrict__ o4) {
    int bx = blockIdx.x;
    int nt = bx % 13;
    int t  = bx / 13;
    int ct = t & 3;   t >>= 2;
    int b  = t & 63;
    int arr = t >> 6;

    const float* in = (arr == 0) ? y1 : (arr == 1) ? y2 : (arr == 2) ? z1 : z2;
    float* outp     = (arr == 0) ? o1 : (arr == 1) ? o2 : (arr == 2) ? o3 : o4;

    __shared__ float tile[64][65];

    int lane = threadIdx.x & 63;
    int w    = threadIdx.x >> 6;
    int n0   = nt * 64;
    int c0   = ct * 64;
    const size_t CN = (size_t)CC * NPIX;

#pragma unroll
    for (int r = 0; r < 16; r++) {
        int cl = w * 16 + r;
        int n  = n0 + lane;
        float v = 0.0f;
        if (n < NPIX) v = in[(size_t)b * CN + (size_t)(c0 + cl) * NPIX + n];
        tile[cl][lane] = v;
    }
    __syncthreads();
#pragma unroll
    for (int r = 0; r < 16; r++) {
        int nl = w * 16 + r;
        int n  = n0 + nl;
        if (n < NPIX)
            outp[((size_t)b * NPIX + n) * CC + c0 + lane] = tile[lane][nl];
    }
}

// ---------------------------------------------------------------------------
// Kernel 2: masked pair cosine sims. One wave per (loss, b, i).
// Mask math replicates numpy fp32 elementwise ops bit-exactly (_rn intrinsics
// prevent FMA contraction; sqrt/div correctly rounded).
// ---------------------------------------------------------------------------
__global__ __launch_bounds__(256) void pairs_k(
    const float* __restrict__ yt1, const float* __restrict__ yt2,
    const float* __restrict__ zt1, const float* __restrict__ zt2,
    const float* __restrict__ g1g, const float* __restrict__ g2g,
    double* __restrict__ acc) {
    int lane = threadIdx.x & 63;
    int wg   = blockIdx.x * 4 + (threadIdx.x >> 6);   // [0, 2*BNP)
    int loss = (wg >= BNP) ? 1 : 0;
    int rem  = wg - loss * BNP;
    int b    = rem / NPIX;
    int i    = rem - b * NPIX;

    const float* g1 = g1g + (size_t)b * 2 * NPIX;  // [2][784]
    const float* g2 = g2g + (size_t)b * 2 * NPIX;

    float g1y = g1[i];
    float g1x = g1[NPIX + i];

    // bin = norm(grid[...,1,1] - grid[...,0,0]) over the 2 channels
    const float* gb = loss ? g2 : g1;
    float d0  = gb[29] - gb[0];                 // (h=1,w=1) idx 29, (0,0) idx 0
    float d1  = gb[NPIX + 29] - gb[NPIX + 0];
    float bin = __fsqrt_rn(__fadd_rn(__fmul_rn(d0, d0), __fmul_rn(d1, d1)));

    // Row feature vector (transposed layout: contiguous 256 floats)
    const float* A = (loss ? yt2 : yt1) + (size_t)(b * NPIX + i) * CC;
    float4 yv = ((const float4*)A)[lane];

    float p = yv.x * yv.x + yv.y * yv.y + yv.z * yv.z + yv.w * yv.w;
#pragma unroll
    for (int off = 32; off; off >>= 1) p += __shfl_xor(p, off);
    float na = __fsqrt_rn(p);

    const float* Zb = (loss ? zt1 : zt2) + (size_t)b * NPIX * CC;

    double ssum = 0.0;
    int    cnt  = 0;

    for (int base = 0; base < NPIX; base += 64) {
        int j = base + lane;
        bool pass = false;
        if (j < NPIX) {
            float dy = g1y - g2[j];
            float dx = g1x - g2[NPIX + j];
            float d  = __fsqrt_rn(__fadd_rn(__fmul_rn(dy, dy), __fmul_rn(dx, dx)));
            pass = (__fdiv_rn(d, bin) <= 0.7f);
        }
        unsigned long long m = __ballot(pass);
        while (m) {
            int bit = __builtin_ctzll(m);
            m &= m - 1;
            int jj = base + bit;
            float4 zv = ((const float4*)(Zb + (size_t)jj * CC))[lane];
            float dp = yv.x * zv.x + yv.y * zv.y + yv.z * zv.z + yv.w * zv.w;
            float zz = zv.x * zv.x + zv.y * zv.y + zv.z * zv.z + zv.w * zv.w;
#pragma unroll
            for (int off = 32; off; off >>= 1) {
                dp += __shfl_xor(dp, off);
                zz += __shfl_xor(zz, off);
            }
            float den = fmaxf(na * __fsqrt_rn(zz), 1e-8f);
            ssum += (double)__fdiv_rn(dp, den);
            cnt++;
        }
    }

    if (lane == 0) {
        int o = loss * 2;
        atomicAdd(&acc[o], ssum);
        atomicAdd(&acc[o + 1], (double)cnt);
    }
}

// ---------------------------------------------------------------------------
// Kernel 3: finalize  loss = -(S0/M0 + S1/M1)
// ---------------------------------------------------------------------------
__global__ void fin_k(const double* __restrict__ acc, float* __restrict__ out) {
    if (threadIdx.x == 0 && blockIdx.x == 0) {
        double l1 = acc[0] / acc[1];
        double l2 = acc[2] / acc[3];
        out[0] = (float)(-(l1 + l2));
    }
}

extern "C" void kernel_launch(void* const* d_in, const int* in_sizes, int n_in,
                              void* d_out, int out_size, void* d_ws, size_t ws_size,
                              hipStream_t stream) {
    const float* y1 = (const float*)d_in[0];
    const float* y2 = (const float*)d_in[1];
    const float* z1 = (const float*)d_in[2];
    const float* z2 = (const float*)d_in[3];
    const float* g1 = (const float*)d_in[4];
    const float* g2 = (const float*)d_in[5];
    float* out = (float*)d_out;

    char* ws = (char*)d_ws;
    double* acc = (double*)ws;                 // [4]: S0, M0, S1, M1
    float* tbase = (float*)(ws + 256);
    const size_t E = (size_t)BB * NPIX * CC;   // 12,845,056 floats per array
    float* yt1 = tbase;
    float* yt2 = tbase + E;
    float* zt1 = tbase + 2 * E;
    float* zt2 = tbase + 3 * E;

    hipMemsetAsync(d_ws, 0, 256, stream);

    // transpose: 4 arrays * 64 b * 4 c-tiles * 13 n-tiles = 13312 blocks
    transpose_k<<<13312, 256, 0, stream>>>(y1, y2, z1, z2, yt1, yt2, zt1, zt2);

    // pairs: 2*BNP waves / 4 waves per block = 25088 blocks
    pairs_k<<<25088, 256, 0, stream>>>(yt1, yt2, zt1, zt2, g1, g2, acc);

    fin_k<<<1, 1, 0, stream>>>(acc, out);
}

// Round 2
// 412.423 us; speedup vs baseline: 6.4635x; 6.4635x over previous
//
#include <hip/hip_runtime.h>
#include <hip/hip_bf16.h>

// Problem constants (from reference): B=64, C=256, H=W=28, N=784
#define BB   64
#define CC   256
#define NPIX 784          // 28*28
#define BNP  (BB * NPIX)  // 50176 (waves per loss)
#define SLOTS 128         // atomic accumulator slots (x4 doubles each)

// ---------------------------------------------------------------------------
// Kernel 1: transpose [B,C,N] -> [B,N,C] for all four feature arrays.
// ---------------------------------------------------------------------------
__global__ __launch_bounds__(256) void transpose_k(
    const float* __restrict__ y1, const float* __restrict__ y2,
    const float* __restrict__ z1, const float* __restrict__ z2,
    float* __restrict__ o1, float* __restrict__ o2,
    float* __restrict__ o3, float* __restrict__ o4) {
    int bx = blockIdx.x;
    int nt = bx % 13;
    int t  = bx / 13;
    int ct = t & 3;   t >>= 2;
    int b  = t & 63;
    int arr = t >> 6;

    const float* in = (arr == 0) ? y1 : (arr == 1) ? y2 : (arr == 2) ? z1 : z2;
    float* outp     = (arr == 0) ? o1 : (arr == 1) ? o2 : (arr == 2) ? o3 : o4;

    __shared__ float tile[64][65];

    int lane = threadIdx.x & 63;
    int w    = threadIdx.x >> 6;
    int n0   = nt * 64;
    int c0   = ct * 64;
    const size_t CN = (size_t)CC * NPIX;

#pragma unroll
    for (int r = 0; r < 16; r++) {
        int cl = w * 16 + r;
        int n  = n0 + lane;
        float v = 0.0f;
        if (n < NPIX) v = in[(size_t)b * CN + (size_t)(c0 + cl) * NPIX + n];
        tile[cl][lane] = v;
    }
    __syncthreads();
#pragma unroll
    for (int r = 0; r < 16; r++) {
        int nl = w * 16 + r;
        int n  = n0 + nl;
        if (n < NPIX)
            outp[((size_t)b * NPIX + n) * CC + c0 + lane] = tile[lane][nl];
    }
}

// ---------------------------------------------------------------------------
// Kernel 2: z-row norms from ORIGINAL layout (coalesced, no reduction).
// znrm[0][b][n] = ||z2[b,:,n]|| (used by loss0), znrm[1][b][n] = ||z1[b,:,n]||
// ---------------------------------------------------------------------------
__global__ __launch_bounds__(256) void norms_k(
    const float* __restrict__ z1, const float* __restrict__ z2,
    float* __restrict__ znrm) {
    int id  = blockIdx.x * 256 + threadIdx.x;   // [0, 2*BNP)
    int arr = id / BNP;
    int rem = id - arr * BNP;
    int b   = rem / NPIX;
    int n   = rem - b * NPIX;
    const float* src = arr ? z1 : z2;
    const float* p = src + (size_t)b * CC * NPIX + n;
    float s = 0.0f;
#pragma unroll 8
    for (int c = 0; c < CC; c++) {
        float v = p[(size_t)c * NPIX];
        s = fmaf(v, v, s);
    }
    znrm[id] = __fsqrt_rn(s);
}

// ---------------------------------------------------------------------------
// Batched pair processing: 8 independent loads + 8 interleaved shfl chains.
// Invalid slots carry duplicated j (valid address); contribution gated by nb.
// ---------------------------------------------------------------------------
__device__ __forceinline__ void batch8(
    const float4 yv, const float* __restrict__ Zb, const float* __restrict__ zn,
    float na, const int* ja, int nb, int lane, double& ssum) {
    float dp[8];
#pragma unroll
    for (int k = 0; k < 8; k++) {
        float4 zv = ((const float4*)(Zb + (size_t)ja[k] * CC))[lane];
        dp[k] = yv.x * zv.x + yv.y * zv.y + yv.z * zv.z + yv.w * zv.w;
    }
#pragma unroll
    for (int off = 32; off; off >>= 1) {
#pragma unroll
        for (int k = 0; k < 8; k++) dp[k] += __shfl_xor(dp[k], off);
    }
#pragma unroll
    for (int k = 0; k < 8; k++) {
        if (k < nb) {
            float den = fmaxf(na * zn[ja[k]], 1e-8f);
            ssum += (double)__fdiv_rn(dp[k], den);
        }
    }
}

// ---------------------------------------------------------------------------
// Kernel 3: masked pair cosine sims. One wave per (loss, b, i).
// Mask math replicates numpy fp32 elementwise ops bit-exactly.
// ---------------------------------------------------------------------------
__global__ __launch_bounds__(256) void pairs_k(
    const float* __restrict__ yt1, const float* __restrict__ yt2,
    const float* __restrict__ zt1, const float* __restrict__ zt2,
    const float* __restrict__ g1g, const float* __restrict__ g2g,
    const float* __restrict__ znrm, double* __restrict__ acc) {
    int lane = threadIdx.x & 63;
    int w    = threadIdx.x >> 6;
    int wg   = blockIdx.x * 4 + w;                    // [0, 2*BNP)
    int loss = (wg >= BNP) ? 1 : 0;
    int rem  = wg - loss * BNP;
    int b    = rem / NPIX;
    int i    = rem - b * NPIX;

    const float* g1 = g1g + (size_t)b * 2 * NPIX;     // [2][784]
    const float* g2 = g2g + (size_t)b * 2 * NPIX;

    float g1y = g1[i];
    float g1x = g1[NPIX + i];

    // bin = norm(grid[...,1,1] - grid[...,0,0])
    const float* gb = loss ? g2 : g1;
    float d0  = gb[29] - gb[0];
    float d1  = gb[NPIX + 29] - gb[NPIX + 0];
    float bin = __fsqrt_rn(__fadd_rn(__fmul_rn(d0, d0), __fmul_rn(d1, d1)));

    // Row feature vector (transposed layout: contiguous 256 floats)
    const float* A = (loss ? yt2 : yt1) + (size_t)(b * NPIX + i) * CC;
    float4 yv = ((const float4*)A)[lane];

    float p = yv.x * yv.x + yv.y * yv.y + yv.z * yv.z + yv.w * yv.w;
#pragma unroll
    for (int off = 32; off; off >>= 1) p += __shfl_xor(p, off);
    float na = __fsqrt_rn(p);

    const float* Zb = (loss ? zt1 : zt2) + (size_t)b * NPIX * CC;
    const float* zn = znrm + (size_t)(loss * BB + b) * NPIX;

    double ssum = 0.0;
    int    cnt  = 0;
    int    nb   = 0;
    int    ja[8] = {0, 0, 0, 0, 0, 0, 0, 0};  // constant-indexed only

    for (int t = 0; t < 13; t++) {
        int j = t * 64 + lane;
        bool pass = false;
        if (j < NPIX) {
            float dy = g1y - g2[j];
            float dx = g1x - g2[NPIX + j];
            float d  = __fsqrt_rn(__fadd_rn(__fmul_rn(dy, dy), __fmul_rn(dx, dx)));
            pass = (__fdiv_rn(d, bin) <= 0.7f);
        }
        unsigned long long m = __ballot(pass);
        while (m) {
            int bt = __builtin_ctzll(m);
            m &= m - 1;
            int jj = t * 64 + bt;
            if      (nb == 0) { ja[0]=jj; ja[1]=jj; ja[2]=jj; ja[3]=jj;
                                ja[4]=jj; ja[5]=jj; ja[6]=jj; ja[7]=jj; }
            else if (nb == 1) ja[1] = jj;
            else if (nb == 2) ja[2] = jj;
            else if (nb == 3) ja[3] = jj;
            else if (nb == 4) ja[4] = jj;
            else if (nb == 5) ja[5] = jj;
            else if (nb == 6) ja[6] = jj;
            else              ja[7] = jj;
            nb++; cnt++;
            if (nb == 8) {
                batch8(yv, Zb, zn, na, ja, 8, lane, ssum);
                nb = 0;
            }
        }
    }
    if (nb) batch8(yv, Zb, zn, na, ja, nb, lane, ssum);

    // Block-level combine, then slot-scattered atomics (kills the R0 hotspot)
    __shared__ double shs[4];
    __shared__ int    shc[4];
    __shared__ int    shl[4];
    if (lane == 0) { shs[w] = ssum; shc[w] = cnt; shl[w] = loss; }
    __syncthreads();
    if (threadIdx.x == 0) {
        double s[2] = {0.0, 0.0};
        double c[2] = {0.0, 0.0};
        for (int k = 0; k < 4; k++) { s[shl[k]] += shs[k]; c[shl[k]] += (double)shc[k]; }
        double* slot = acc + (size_t)(blockIdx.x & (SLOTS - 1)) * 4;
        if (s[0] != 0.0 || c[0] != 0.0) { atomicAdd(&slot[0], s[0]); atomicAdd(&slot[1], c[0]); }
        if (s[1] != 0.0 || c[1] != 0.0) { atomicAdd(&slot[2], s[1]); atomicAdd(&slot[3], c[1]); }
    }
}

// ---------------------------------------------------------------------------
// Kernel 4: finalize  loss = -(S0/M0 + S1/M1)  (reduce the 128 slots)
// ---------------------------------------------------------------------------
__global__ void fin_k(const double* __restrict__ acc, float* __restrict__ out) {
    int lane = threadIdx.x;   // 64 threads
    double s0 = 0, m0 = 0, s1 = 0, m1 = 0;
    for (int s = lane; s < SLOTS; s += 64) {
        const double* p = acc + (size_t)s * 4;
        s0 += p[0]; m0 += p[1]; s1 += p[2]; m1 += p[3];
    }
#pragma unroll
    for (int off = 32; off; off >>= 1) {
        s0 += __shfl_xor(s0, off); m0 += __shfl_xor(m0, off);
        s1 += __shfl_xor(s1, off); m1 += __shfl_xor(m1, off);
    }
    if (lane == 0) out[0] = (float)(-(s0 / m0 + s1 / m1));
}

extern "C" void kernel_launch(void* const* d_in, const int* in_sizes, int n_in,
                              void* d_out, int out_size, void* d_ws, size_t ws_size,
                              hipStream_t stream) {
    const float* y1 = (const float*)d_in[0];
    const float* y2 = (const float*)d_in[1];
    const float* z1 = (const float*)d_in[2];
    const float* z2 = (const float*)d_in[3];
    const float* g1 = (const float*)d_in[4];
    const float* g2 = (const float*)d_in[5];
    float* out = (float*)d_out;

    char* ws = (char*)d_ws;
    double* acc = (double*)ws;                       // SLOTS*4 doubles = 4 KB
    float* znrm = (float*)(ws + 4096);               // 2*BNP floats = 401,408 B
    float* tbase = (float*)(ws + 4096 + 2 * BNP * sizeof(float));
    const size_t E = (size_t)BB * NPIX * CC;         // 12,845,056 floats per array
    float* yt1 = tbase;
    float* yt2 = tbase + E;
    float* zt1 = tbase + 2 * E;
    float* zt2 = tbase + 3 * E;

    hipMemsetAsync(acc, 0, SLOTS * 4 * sizeof(double), stream);

    // transpose: 4 arrays * 64 b * 4 c-tiles * 13 n-tiles = 13312 blocks
    transpose_k<<<13312, 256, 0, stream>>>(y1, y2, z1, z2, yt1, yt2, zt1, zt2);

    // norms of z2 (loss0) and z1 (loss1): 2*BNP threads / 256 = 392 blocks
    norms_k<<<392, 256, 0, stream>>>(z1, z2, znrm);

    // pairs: 2*BNP waves / 4 waves per block = 25088 blocks
    pairs_k<<<25088, 256, 0, stream>>>(yt1, yt2, zt1, zt2, g1, g2, znrm, acc);

    fin_k<<<1, 64, 0, stream>>>(acc, out);
}

// Round 3
// 289.203 us; speedup vs baseline: 9.2175x; 1.4261x over previous
//
#include <hip/hip_runtime.h>
#include <hip/hip_bf16.h>

// Problem constants: B=64, C=256, H=W=28, N=784
#define BB   64
#define CC   256
#define NPIX 784
#define BNP  (BB * NPIX)   // 50176
#define SLOTS 128

// ---------------------------------------------------------------------------
// Kernel 1: transpose [B,C,N] -> [B,N,C] for all four arrays, float4 both
// sides (1 KB per wave memory instruction), with fused squared-norm partials
// (16-lane shfl reduce + one f32 atomic per (arr,b,n) per c-tile).
// grid: bx = ((arr*64 + b)*4 + ct)*13 + nt
// ---------------------------------------------------------------------------
__global__ __launch_bounds__(256) void transpose_k(
    const float* __restrict__ y1, const float* __restrict__ y2,
    const float* __restrict__ z1, const float* __restrict__ z2,
    float* __restrict__ o1, float* __restrict__ o2,
    float* __restrict__ o3, float* __restrict__ o4,
    float* __restrict__ nrm2) {
    int bx = blockIdx.x;
    int nt = bx % 13;
    int t  = bx / 13;
    int ct = t & 3;   t >>= 2;
    int b  = t & 63;
    int arr = t >> 6;

    const float* in = (arr == 0) ? y1 : (arr == 1) ? y2 : (arr == 2) ? z1 : z2;
    float* outp     = (arr == 0) ? o1 : (arr == 1) ? o2 : (arr == 2) ? o3 : o4;

    __shared__ float tile[64][65];

    int tid = threadIdx.x;
    int hi  = tid >> 4;   // 0..15
    int lo  = tid & 15;   // 0..15
    int n0  = nt * 64;
    int c0  = ct * 64;
    const float* inb = in + (size_t)b * (CC * NPIX);

    // read: per wave 4 c-rows x 64 n (float4 along n) = 1 KB / instr
#pragma unroll
    for (int k = 0; k < 4; k++) {
        int c = c0 + hi + 16 * k;
        int n = n0 + 4 * lo;
        float4 v = {0.f, 0.f, 0.f, 0.f};
        if (n < NPIX) v = *(const float4*)(inb + (size_t)c * NPIX + n);
        tile[hi + 16 * k][4 * lo + 0] = v.x;
        tile[hi + 16 * k][4 * lo + 1] = v.y;
        tile[hi + 16 * k][4 * lo + 2] = v.z;
        tile[hi + 16 * k][4 * lo + 3] = v.w;
    }
    __syncthreads();

    float* nrow = nrm2 + ((size_t)arr * BB + b) * NPIX;
    // write: per wave 4 n-rows x 64 c (float4 along c) = 1 KB / instr
#pragma unroll
    for (int k = 0; k < 4; k++) {
        int nl = hi + 16 * k;
        int n  = n0 + nl;
        float4 v;
        v.x = tile[4 * lo + 0][nl];
        v.y = tile[4 * lo + 1][nl];
        v.z = tile[4 * lo + 2][nl];
        v.w = tile[4 * lo + 3][nl];
        bool ok = (n < NPIX);
        if (ok)
            *(float4*)(outp + ((size_t)b * NPIX + n) * CC + c0 + 4 * lo) = v;
        // fused squared-norm partial over this thread's 4 channels
        float p = fmaf(v.x, v.x, fmaf(v.y, v.y, fmaf(v.z, v.z, v.w * v.w)));
#pragma unroll
        for (int off = 1; off < 16; off <<= 1) p += __shfl_xor(p, off);
        if (ok && lo == 0) atomicAdd(&nrow[n], p);
    }
}

// ---------------------------------------------------------------------------
// Kernel 2: masked pair cosine sims. One wave per (loss, b, i).
// Box-pruned candidates (<=3x3 lattice box, guard-widened), bit-exact mask
// eval on candidate lanes, 16-lane-group dots (4 pairs per batch).
// ---------------------------------------------------------------------------
__global__ __launch_bounds__(256) void pairs_k(
    const float* __restrict__ yt1, const float* __restrict__ yt2,
    const float* __restrict__ zt1, const float* __restrict__ zt2,
    const float* __restrict__ g1g, const float* __restrict__ g2g,
    const float* __restrict__ nrm2, double* __restrict__ acc) {
    int lane = threadIdx.x & 63;
    int w    = threadIdx.x >> 6;
    int wg   = blockIdx.x * 4 + w;                 // [0, 2*BNP)
    int loss = (wg >= BNP) ? 1 : 0;
    int rem  = wg - loss * BNP;
    int b    = rem / NPIX;
    int i    = rem - b * NPIX;

    const float* g1 = g1g + (size_t)b * 2 * NPIX;
    const float* g2 = g2g + (size_t)b * 2 * NPIX;

    float g1y = g1[i];
    float g1x = g1[NPIX + i];

    // bin = norm(grid[...,1,1] - grid[...,0,0])  (bit-exact chain)
    const float* gb = loss ? g2 : g1;
    float d0  = gb[29] - gb[0];
    float d1  = gb[NPIX + 29] - gb[NPIX];
    float bin = __fsqrt_rn(__fadd_rn(__fmul_rn(d0, d0), __fmul_rn(d1, d1)));

    // candidate box in grid2 index space (guards >> fp slop; exact test below)
    float t2y = g2[0], t2x = g2[NPIX];
    float s2y = g2[28] - g2[0];            // y step (h=1,w=0) - (0,0)
    float s2x = g2[NPIX + 1] - g2[NPIX];   // x step (h=0,w=1) - (0,0)
    float r  = 0.7f * bin * 1.0002f + 1e-4f;
    float cy = (g1y - t2y) / s2y;
    float cx = (g1x - t2x) / s2x;
    float ry = r / s2y + 0.05f;
    float rx = r / s2x + 0.05f;
    int jy0 = max(0,  (int)ceilf(cy - ry));
    int jy1 = min(27, (int)floorf(cy + ry));
    int jx0 = max(0,  (int)ceilf(cx - rx));
    int jx1 = min(27, (int)floorf(cx + rx));
    int dyr = jy1 - jy0, dxr = jx1 - jx0;  // may be negative (empty box)

    // candidate lanes: lane = dy*4 + dx
    int dyl = lane >> 2, dxl = lane & 3;
    bool pass = false;
    if (dyl <= dyr && dxl <= dxr) {
        int jc = (jy0 + dyl) * 28 + jx0 + dxl;
        float dy = g1y - g2[jc];
        float dx = g1x - g2[NPIX + jc];
        float d  = __fsqrt_rn(__fadd_rn(__fmul_rn(dy, dy), __fmul_rn(dx, dx)));
        pass = (__fdiv_rn(d, bin) <= 0.7f);   // bit-exact mask decision
    }
    unsigned long long m = __ballot(pass);
    int cnt = __builtin_popcountll(m);

    const float* Y   = (loss ? yt2 : yt1) + ((size_t)b * NPIX + i) * CC;
    const float* Zb  = (loss ? zt1 : zt2) + (size_t)b * NPIX * CC;
    const float* zn2 = nrm2 + ((size_t)(loss ? 2 : 3) * BB + b) * NPIX;
    float yn2 = nrm2[((size_t)loss * BB + b) * NPIX + i];
    float na  = __fsqrt_rn(yn2);

    int gl = lane & 15;        // lane within 16-lane group
    int g  = lane >> 4;        // group id 0..3

    float4 ych[4];
    if (m) {
        const float4* Y4 = (const float4*)Y;
        ych[0] = Y4[gl];
        ych[1] = Y4[gl + 16];
        ych[2] = Y4[gl + 32];
        ych[3] = Y4[gl + 48];
    }

    double ssum = 0.0;
    while (m) {
        int bt = __builtin_ctzll(m); m &= m - 1;
        int j0 = (jy0 + (bt >> 2)) * 28 + jx0 + (bt & 3);
        int j1 = j0, j2 = j0, j3 = j0;
        int nb = 1;
        if (m) {
            bt = __builtin_ctzll(m); m &= m - 1;
            j1 = (jy0 + (bt >> 2)) * 28 + jx0 + (bt & 3); nb = 2;
            if (m) {
                bt = __builtin_ctzll(m); m &= m - 1;
                j2 = (jy0 + (bt >> 2)) * 28 + jx0 + (bt & 3); nb = 3;
                if (m) {
                    bt = __builtin_ctzll(m); m &= m - 1;
                    j3 = (jy0 + (bt >> 2)) * 28 + jx0 + (bt & 3); nb = 4;
                }
            }
        }
        int js = (g == 0) ? j0 : (g == 1) ? j1 : (g == 2) ? j2 : j3;
        const float4* Z4 = (const float4*)(Zb + (size_t)js * CC);
        float4 zv0 = Z4[gl];
        float4 zv1 = Z4[gl + 16];
        float4 zv2 = Z4[gl + 32];
        float4 zv3 = Z4[gl + 48];
        float dp = ych[0].x * zv0.x;
        dp = fmaf(ych[0].y, zv0.y, dp); dp = fmaf(ych[0].z, zv0.z, dp);
        dp = fmaf(ych[0].w, zv0.w, dp);
        dp = fmaf(ych[1].x, zv1.x, dp); dp = fmaf(ych[1].y, zv1.y, dp);
        dp = fmaf(ych[1].z, zv1.z, dp); dp = fmaf(ych[1].w, zv1.w, dp);
        dp = fmaf(ych[2].x, zv2.x, dp); dp = fmaf(ych[2].y, zv2.y, dp);
        dp = fmaf(ych[2].z, zv2.z, dp); dp = fmaf(ych[2].w, zv2.w, dp);
        dp = fmaf(ych[3].x, zv3.x, dp); dp = fmaf(ych[3].y, zv3.y, dp);
        dp = fmaf(ych[3].z, zv3.z, dp); dp = fmaf(ych[3].w, zv3.w, dp);
#pragma unroll
        for (int off = 1; off < 16; off <<= 1) dp += __shfl_xor(dp, off);
        float den = fmaxf(na * __fsqrt_rn(zn2[js]), 1e-8f);
        float sim = __fdividef(dp, den);
        if (g < nb) ssum += (double)sim;
    }
    // combine 4 groups (lanes within a group hold identical ssum)
    ssum += __shfl_xor(ssum, 16);
    ssum += __shfl_xor(ssum, 32);

    // block combine + slot-scattered atomics
    __shared__ double shs[4];
    __shared__ int    shc[4];
    __shared__ int    shl[4];
    if (lane == 0) { shs[w] = ssum; shc[w] = cnt; shl[w] = loss; }
    __syncthreads();
    if (threadIdx.x == 0) {
        double s[2] = {0.0, 0.0};
        double c[2] = {0.0, 0.0};
        for (int k = 0; k < 4; k++) { s[shl[k]] += shs[k]; c[shl[k]] += (double)shc[k]; }
        double* slot = acc + (size_t)(blockIdx.x & (SLOTS - 1)) * 4;
        if (s[0] != 0.0 || c[0] != 0.0) { atomicAdd(&slot[0], s[0]); atomicAdd(&slot[1], c[0]); }
        if (s[1] != 0.0 || c[1] != 0.0) { atomicAdd(&slot[2], s[1]); atomicAdd(&slot[3], c[1]); }
    }
}

// ---------------------------------------------------------------------------
// Kernel 3: finalize  loss = -(S0/M0 + S1/M1)
// ---------------------------------------------------------------------------
__global__ void fin_k(const double* __restrict__ acc, float* __restrict__ out) {
    int lane = threadIdx.x;   // 64 threads
    double s0 = 0, m0 = 0, s1 = 0, m1 = 0;
    for (int s = lane; s < SLOTS; s += 64) {
        const double* p = acc + (size_t)s * 4;
        s0 += p[0]; m0 += p[1]; s1 += p[2]; m1 += p[3];
    }
#pragma unroll
    for (int off = 32; off; off >>= 1) {
        s0 += __shfl_xor(s0, off); m0 += __shfl_xor(m0, off);
        s1 += __shfl_xor(s1, off); m1 += __shfl_xor(m1, off);
    }
    if (lane == 0) out[0] = (float)(-(s0 / m0 + s1 / m1));
}

extern "C" void kernel_launch(void* const* d_in, const int* in_sizes, int n_in,
                              void* d_out, int out_size, void* d_ws, size_t ws_size,
                              hipStream_t stream) {
    const float* y1 = (const float*)d_in[0];
    const float* y2 = (const float*)d_in[1];
    const float* z1 = (const float*)d_in[2];
    const float* z2 = (const float*)d_in[3];
    const float* g1 = (const float*)d_in[4];
    const float* g2 = (const float*)d_in[5];
    float* out = (float*)d_out;

    char* ws = (char*)d_ws;
    double* acc  = (double*)ws;                        // SLOTS*4 doubles = 4 KB
    float*  nrm2 = (float*)(ws + 4096);                // 4*BNP floats = 802,816 B
    float*  tbase = (float*)(ws + 4096 + 4 * BNP * sizeof(float));  // 16B aligned
    const size_t E = (size_t)BB * NPIX * CC;           // 12,845,056 floats / array
    float* yt1 = tbase;
    float* yt2 = tbase + E;
    float* zt1 = tbase + 2 * E;
    float* zt2 = tbase + 3 * E;

    // zero acc + nrm2 in one shot
    hipMemsetAsync(ws, 0, 4096 + 4 * BNP * sizeof(float), stream);

    // transpose+norms: 4 arrays * 64 b * 4 c-tiles * 13 n-tiles = 13312 blocks
    transpose_k<<<13312, 256, 0, stream>>>(y1, y2, z1, z2, yt1, yt2, zt1, zt2, nrm2);

    // pairs: 2*BNP waves / 4 waves per block = 25088 blocks
    pairs_k<<<25088, 256, 0, stream>>>(yt1, yt2, zt1, zt2, g1, g2, nrm2, acc);

    fin_k<<<1, 64, 0, stream>>>(acc, out);
}